// Round 1
// baseline (688.146 us; speedup 1.0000x reference)
//
#include <hip/hip_runtime.h>
#include <hip/hip_bf16.h>

// Problem constants
#define BB 8
#define NN 16384
#define MM 4096
#define C1 64
#define C2 256
#define K1 320            // C1 + C2
#define CO 256
#define MTOT (BB * NN)    // 131072

// Workspace layout (bytes)
#define STATS_OFF 0                 // 8*256 floats
#define FLAG_OFF  8192
#define W1B_OFF   16384             // bf16 256x320
#define W2B_OFF   180224            // bf16 256x256
#define F2T_OFF   327680            // bf16 [B,M,C2] = 16777216 B
#define XT_OFF    (327680 + 16777216)              // bf16 [MTOT,320]
#define H2_OFF    (327680 + 16777216 + 83886080)   // bf16 [B,CO,N]

typedef short v8s __attribute__((ext_vector_type(8)));
typedef float v4f __attribute__((ext_vector_type(4)));

__device__ __forceinline__ float bf2f(unsigned short u) {
    unsigned v = ((unsigned)u) << 16;
    float f;
    __builtin_memcpy(&f, &v, 4);
    return f;
}
__device__ __forceinline__ unsigned short f2bf(float f) {
    unsigned u;
    __builtin_memcpy(&u, &f, 4);
    unsigned r = u + 0x7fffu + ((u >> 16) & 1u);  // RNE
    return (unsigned short)(r >> 16);
}
__device__ __forceinline__ void gload16(const unsigned short* g, unsigned short* l) {
    __builtin_amdgcn_global_load_lds((const __attribute__((address_space(1))) unsigned int*)g,
                                     (__attribute__((address_space(3))) unsigned int*)l, 16, 0, 0);
}

// ---------------- prep: zero stats, idx width flag, W1/W2 -> bf16 ----------
__global__ void k_prep(const void* idx_raw, int* flag64, float* stats,
                       const float* __restrict__ W1, unsigned short* __restrict__ W1b,
                       const float* __restrict__ W2, unsigned short* __restrict__ W2b) {
    int blk = blockIdx.x;
    int t = threadIdx.x;
    if (blk < 320) {
        int e = blk * 256 + t;
        W1b[e] = f2bf(W1[e]);
    } else if (blk < 576) {
        int e = (blk - 320) * 256 + t;
        W2b[e] = f2bf(W2[e]);
    } else {
        for (int i = t; i < 8 * 256; i += 256) stats[i] = 0.f;
        if (t == 0) {
            const int* a = (const int*)idx_raw;
            int all0 = 1;
            for (int j = 1; j < 64; j += 2) all0 &= (a[j] == 0);
            *flag64 = all0;  // 1 => idx int64
        }
    }
}

// ------- transpose f2 [B,C2,M] -> f2t bf16 [B,M,C2]; 64ch x 32m tiles ------
__global__ void k_tr_f2(const float* __restrict__ f2, unsigned short* __restrict__ f2t) {
    __shared__ float tile[64][33];
    int b = blockIdx.z;
    int c0 = blockIdx.y * 64;
    int m0 = blockIdx.x * 32;
    int t = threadIdx.x;
    int lm = t & 31, lc = t >> 5;          // lc 0..7
    const float* src = f2 + ((size_t)b * C2 + c0) * MM + m0;
#pragma unroll
    for (int j = 0; j < 8; ++j)
        tile[lc + 8 * j][lm] = src[(size_t)(lc + 8 * j) * MM + lm];
    __syncthreads();
    int m = t >> 3, c8 = (t & 7) * 8;      // m 0..31, c8 0..56
    unsigned short tmp[8];
#pragma unroll
    for (int k = 0; k < 8; ++k) tmp[k] = f2bf(tile[c8 + k][m]);
    uint4 v;
    v.x = (unsigned)tmp[0] | ((unsigned)tmp[1] << 16);
    v.y = (unsigned)tmp[2] | ((unsigned)tmp[3] << 16);
    v.z = (unsigned)tmp[4] | ((unsigned)tmp[5] << 16);
    v.w = (unsigned)tmp[6] | ((unsigned)tmp[7] << 16);
    *(uint4*)&f2t[((size_t)b * MM + m0 + m) * C2 + c0 + c8] = v;
}

// ------- transpose f1 [B,C1,N] -> xT[:,0:64] bf16; 64ch x 32n tiles --------
__global__ void k_tr_f1(const float* __restrict__ f1, unsigned short* __restrict__ xT) {
    __shared__ float tile[64][33];
    int b = blockIdx.z;
    int n0 = blockIdx.x * 32;
    int t = threadIdx.x;
    int lm = t & 31, lc = t >> 5;
    const float* src = f1 + ((size_t)b * C1) * NN + n0;
#pragma unroll
    for (int j = 0; j < 8; ++j)
        tile[lc + 8 * j][lm] = src[(size_t)(lc + 8 * j) * NN + lm];
    __syncthreads();
    int m = t >> 3, c8 = (t & 7) * 8;
    unsigned short tmp[8];
#pragma unroll
    for (int k = 0; k < 8; ++k) tmp[k] = f2bf(tile[c8 + k][m]);
    uint4 v;
    v.x = (unsigned)tmp[0] | ((unsigned)tmp[1] << 16);
    v.y = (unsigned)tmp[2] | ((unsigned)tmp[3] << 16);
    v.z = (unsigned)tmp[4] | ((unsigned)tmp[5] << 16);
    v.w = (unsigned)tmp[6] | ((unsigned)tmp[7] << 16);
    *(uint4*)&xT[((size_t)b * NN + n0 + m) * K1 + c8] = v;
}

// ---------------- 3-NN inverse-distance interpolation -> xT[:,64:320] -------
__global__ void k_interp(const float* __restrict__ p1, const float* __restrict__ p2,
                         const void* __restrict__ idxv, const int* __restrict__ flag64,
                         const unsigned short* __restrict__ f2t,
                         unsigned short* __restrict__ xT) {
    int t = threadIdx.x;
    int p = t >> 5, lane = t & 31;
    size_t pt = (size_t)blockIdx.x * 8 + p;
    int b = (int)(pt >> 14);
    int m0, m1, m2;
    if (*flag64) {
        const long long* id = (const long long*)idxv;
        m0 = (int)id[pt * 3 + 0]; m1 = (int)id[pt * 3 + 1]; m2 = (int)id[pt * 3 + 2];
    } else {
        const int* id = (const int*)idxv;
        m0 = id[pt * 3 + 0]; m1 = id[pt * 3 + 1]; m2 = id[pt * 3 + 2];
    }
    float qx = p1[pt * 3 + 0], qy = p1[pt * 3 + 1], qz = p1[pt * 3 + 2];
    const float* pb = p2 + (size_t)b * MM * 3;
    float dx, dy, dz;
    dx = qx - pb[m0 * 3 + 0]; dy = qy - pb[m0 * 3 + 1]; dz = qz - pb[m0 * 3 + 2];
    float d0 = dx * dx + dy * dy + dz * dz;
    dx = qx - pb[m1 * 3 + 0]; dy = qy - pb[m1 * 3 + 1]; dz = qz - pb[m1 * 3 + 2];
    float d1 = dx * dx + dy * dy + dz * dz;
    dx = qx - pb[m2 * 3 + 0]; dy = qy - pb[m2 * 3 + 1]; dz = qz - pb[m2 * 3 + 2];
    float d2v = dx * dx + dy * dy + dz * dz;
    float r0 = 1.f / (d0 + 1e-8f), r1 = 1.f / (d1 + 1e-8f), r2 = 1.f / (d2v + 1e-8f);
    float inv = 1.f / (r0 + r1 + r2);
    float w0 = r0 * inv, w1 = r1 * inv, w2 = r2 * inv;

    const unsigned short* fb = f2t + (size_t)b * MM * C2;
    int c0 = lane * 8;
    uint4 va = *(const uint4*)(fb + (size_t)m0 * C2 + c0);
    uint4 vb = *(const uint4*)(fb + (size_t)m1 * C2 + c0);
    uint4 vc = *(const uint4*)(fb + (size_t)m2 * C2 + c0);

    float r[8];
    {
        const unsigned av[4] = {va.x, va.y, va.z, va.w};
        const unsigned bv[4] = {vb.x, vb.y, vb.z, vb.w};
        const unsigned cv[4] = {vc.x, vc.y, vc.z, vc.w};
#pragma unroll
        for (int q = 0; q < 4; ++q) {
            r[2 * q + 0] = w0 * bf2f((unsigned short)(av[q] & 0xffff))
                         + w1 * bf2f((unsigned short)(bv[q] & 0xffff))
                         + w2 * bf2f((unsigned short)(cv[q] & 0xffff));
            r[2 * q + 1] = w0 * bf2f((unsigned short)(av[q] >> 16))
                         + w1 * bf2f((unsigned short)(bv[q] >> 16))
                         + w2 * bf2f((unsigned short)(cv[q] >> 16));
        }
    }
    uint4 outv;
    outv.x = (unsigned)f2bf(r[0]) | ((unsigned)f2bf(r[1]) << 16);
    outv.y = (unsigned)f2bf(r[2]) | ((unsigned)f2bf(r[3]) << 16);
    outv.z = (unsigned)f2bf(r[4]) | ((unsigned)f2bf(r[5]) << 16);
    outv.w = (unsigned)f2bf(r[6]) | ((unsigned)f2bf(r[7]) << 16);
    *(uint4*)(xT + pt * K1 + C1 + c0) = outv;
}

// ================= MFMA GEMM1: h1 = xT @ W1^T (bf16), + BN1 stats ==========
// Swapped operands (A=W1 frag, B=x frag) => lane holds 4 consecutive co for a
// fixed n => direct 8B packed stores, no LDS epilogue.
// Double-buffered LDS, counted vmcnt(8), raw barriers, XOR-swizzled layout
// (pre-swizzled global source since global_load_lds dest must be linear).
#define TM 128
#define TN 128
#define TK 64
__launch_bounds__(256)
__global__ void k_gemm1(const unsigned short* __restrict__ xT,
                        const unsigned short* __restrict__ W1b,
                        unsigned short* __restrict__ h1,
                        float* __restrict__ sum1, float* __restrict__ ssq1) {
    __shared__ unsigned short smem[2][TM * TK + TN * TK];   // [buf][ Xs | Ws ]
    const int t = threadIdx.x;
    const int lane = t & 63, w = t >> 6;
    const int cosub = (w >> 1) * 64;   // wave's co sub-block
    const int nsub = (w & 1) * 64;     // wave's n sub-block
    const long rbase = (long)blockIdx.x * TM;   // n base
    const int cb = blockIdx.y * TN;             // co base

    v4f acc[4][4];   // [r=co-tile][c=n-tile]
#pragma unroll
    for (int r = 0; r < 4; ++r)
#pragma unroll
        for (int c = 0; c < 4; ++c) acc[r][c] = (v4f)(0.f);

    const int srow = w * 32 + (lane >> 3);
    // pre-swizzled global column: LDS slot s holds G[row][s ^ (row&7)*8]
    const int sch = ((lane & 7) ^ ((lane >> 3) & 7)) * 8;
    const unsigned short* Ag = xT + (rbase + srow) * K1 + sch;              // x rows (n)
    const unsigned short* Bg = W1b + (size_t)(cb + srow) * K1 + sch;        // W rows (co)

    // prologue: stage tile 0 into buf 0
#pragma unroll
    for (int j = 0; j < 4; ++j) {
        gload16(Ag + (size_t)(j * 8) * K1, smem[0] + (w * 32 + j * 8) * TK);
        gload16(Bg + (size_t)(j * 8) * K1, smem[0] + TM * TK + (w * 32 + j * 8) * TK);
    }

    const int ln = lane & 15, q = lane >> 4;
    const int xr = (lane & 7) * 8;   // read-side XOR ((row&7)*8 with row=..+ln)

#pragma unroll
    for (int k0 = 0; k0 < K1; k0 += TK) {
        const int p = (k0 >> 6) & 1;
        if (k0 + TK < K1) {
            // stage next tile into the other buffer (8 vmem ops)
#pragma unroll
            for (int j = 0; j < 4; ++j) {
                gload16(Ag + (size_t)(j * 8) * K1 + k0 + TK, smem[p ^ 1] + (w * 32 + j * 8) * TK);
                gload16(Bg + (size_t)(j * 8) * K1 + k0 + TK, smem[p ^ 1] + TM * TK + (w * 32 + j * 8) * TK);
            }
            // wait only for the CURRENT tile's 8 loads; next tile stays in flight
            asm volatile("s_waitcnt vmcnt(8)" ::: "memory");
        } else {
            asm volatile("s_waitcnt vmcnt(0)" ::: "memory");
        }
        asm volatile("s_barrier" ::: "memory");   // all waves' tile-k loads visible
        const unsigned short* Xs = smem[p];
        const unsigned short* Ws = smem[p] + TM * TK;
#pragma unroll
        for (int ks = 0; ks < 2; ++ks) {
            const int off = (q * 8 + ks * 32) ^ xr;
            v8s af[4], bx[4];
#pragma unroll
            for (int r = 0; r < 4; ++r) af[r] = *(const v8s*)(Ws + (cosub + r * 16 + ln) * TK + off);
#pragma unroll
            for (int c = 0; c < 4; ++c) bx[c] = *(const v8s*)(Xs + (nsub + c * 16 + ln) * TK + off);
#pragma unroll
            for (int r = 0; r < 4; ++r)
#pragma unroll
                for (int c = 0; c < 4; ++c)
                    acc[r][c] = __builtin_amdgcn_mfma_f32_16x16x32_bf16(af[r], bx[c], acc[r][c], 0, 0, 0);
        }
        // protect this buffer's reads from next iteration's staging
        if (k0 + TK < K1) asm volatile("s_barrier" ::: "memory");
    }

    // ---- epilogue: direct packed stores (lane holds 4 consecutive co) + stats
    float s[4][4], sq[4][4];
#pragma unroll
    for (int r = 0; r < 4; ++r)
#pragma unroll
        for (int i = 0; i < 4; ++i) { s[r][i] = 0.f; sq[r][i] = 0.f; }
#pragma unroll
    for (int r = 0; r < 4; ++r) {
#pragma unroll
        for (int c = 0; c < 4; ++c) {
            float v0 = acc[r][c][0], v1 = acc[r][c][1], v2 = acc[r][c][2], v3 = acc[r][c][3];
            uint2 ov;
            ov.x = (unsigned)f2bf(v0) | ((unsigned)f2bf(v1) << 16);
            ov.y = (unsigned)f2bf(v2) | ((unsigned)f2bf(v3) << 16);
            *(uint2*)&h1[(size_t)(rbase + nsub + c * 16 + ln) * CO + cb + cosub + r * 16 + q * 4] = ov;
            s[r][0] += v0; sq[r][0] += v0 * v0;
            s[r][1] += v1; sq[r][1] += v1 * v1;
            s[r][2] += v2; sq[r][2] += v2 * v2;
            s[r][3] += v3; sq[r][3] += v3 * v3;
        }
    }
    // reduce over the 16 n-lanes (xor masks stay within the q-group)
#pragma unroll
    for (int m = 1; m <= 8; m <<= 1) {
#pragma unroll
        for (int r = 0; r < 4; ++r)
#pragma unroll
            for (int i = 0; i < 4; ++i) {
                s[r][i] += __shfl_xor(s[r][i], m);
                sq[r][i] += __shfl_xor(sq[r][i], m);
            }
    }
    if (ln == 0) {
#pragma unroll
        for (int r = 0; r < 4; ++r)
#pragma unroll
            for (int i = 0; i < 4; ++i) {
                atomicAdd(&sum1[cb + cosub + r * 16 + q * 4 + i], s[r][i]);
                atomicAdd(&ssq1[cb + cosub + r * 16 + q * 4 + i], sq[r][i]);
            }
    }
}

// ====== MFMA GEMM2: h2 = relu(bn1(h1)) @ W2^T -> [B,CO,N] + BN2 stats =======
// Normal orientation => lane holds 4 consecutive n for fixed co => direct 8B
// stores into [B,CO,N]. A staged via reg->BN->ds_write (swizzled slot),
// B via pre-swizzled global_load_lds. Same counted-vmcnt double buffer.
__launch_bounds__(256)
__global__ void k_gemm2(const unsigned short* __restrict__ h1,
                        const unsigned short* __restrict__ W2b,
                        const float* __restrict__ sum1, const float* __restrict__ ssq1,
                        const float* __restrict__ g1, const float* __restrict__ b1,
                        unsigned short* __restrict__ h2,
                        float* __restrict__ sum2, float* __restrict__ ssq2) {
    __shared__ unsigned short smem[2][TM * TK + TN * TK];   // [buf][ As | Ws ]
    __shared__ float sc1[CO], sh1[CO];
    const int t = threadIdx.x;
    const int lane = t & 63, w = t >> 6;
    const int nsub = (w >> 1) * 64;
    const int cosub = (w & 1) * 64;
    const long rbase = (long)blockIdx.x * TM;
    const int cb = blockIdx.y * TN;

    // fold BN1 finalize (stream-ordered after gemm1)
    {
        const float invn = 1.f / (float)MTOT;
        float m = sum1[t] * invn;
        float v = ssq1[t] * invn - m * m;
        float sgl = g1[t] * rsqrtf(v + 1e-5f);
        sc1[t] = sgl;
        sh1[t] = b1[t] - m * sgl;
    }
    __syncthreads();

    v4f acc[4][4];   // [r=n-tile][c=co-tile]
#pragma unroll
    for (int r = 0; r < 4; ++r)
#pragma unroll
        for (int c = 0; c < 4; ++c) acc[r][c] = (v4f)(0.f);

    const int srow = w * 32 + (lane >> 3);
    const int schl = (lane & 7) * 8;                              // linear col (A reg loads)
    const int sch = ((lane & 7) ^ ((lane >> 3) & 7)) * 8;         // swizzled col/slot
    const unsigned short* Ag = h1 + (rbase + srow) * CO + schl;
    const unsigned short* Bg = W2b + (size_t)(cb + srow) * CO + sch;

    // prologue: A(0) into regs, W(0) into buf 0
    uint4 avc[4];
#pragma unroll
    for (int j = 0; j < 4; ++j) avc[j] = *(const uint4*)(Ag + (size_t)(j * 8) * CO);
#pragma unroll
    for (int j = 0; j < 4; ++j)
        gload16(Bg + (size_t)(j * 8) * CO, smem[0] + TM * TK + (w * 32 + j * 8) * TK);

    const int ln = lane & 15, q = lane >> 4;
    const int xr = (lane & 7) * 8;

#pragma unroll
    for (int k0 = 0; k0 < CO; k0 += TK) {
        const int p = (k0 >> 6) & 1;
        const bool notlast = (k0 + TK < CO);
        uint4 avn[4];
        if (notlast) {
#pragma unroll
            for (int j = 0; j < 4; ++j)
                avn[j] = *(const uint4*)(Ag + (size_t)(j * 8) * CO + k0 + TK);
        }
        // convert current A tile (BN1+ReLU) -> ds_write at swizzled slot
        {
            float4 sca = *(const float4*)(sc1 + k0 + schl);
            float4 scb = *(const float4*)(sc1 + k0 + schl + 4);
            float4 sha = *(const float4*)(sh1 + k0 + schl);
            float4 shb = *(const float4*)(sh1 + k0 + schl + 4);
            unsigned short* dst = smem[p] + srow * TK + sch;
#pragma unroll
            for (int j = 0; j < 4; ++j) {
                uint4 av = avc[j];
                float y0 = fmaxf(bf2f((unsigned short)(av.x & 0xffff)) * sca.x + sha.x, 0.f);
                float y1 = fmaxf(bf2f((unsigned short)(av.x >> 16)) * sca.y + sha.y, 0.f);
                float y2 = fmaxf(bf2f((unsigned short)(av.y & 0xffff)) * sca.z + sha.z, 0.f);
                float y3 = fmaxf(bf2f((unsigned short)(av.y >> 16)) * sca.w + sha.w, 0.f);
                float y4 = fmaxf(bf2f((unsigned short)(av.z & 0xffff)) * scb.x + shb.x, 0.f);
                float y5 = fmaxf(bf2f((unsigned short)(av.z >> 16)) * scb.y + shb.y, 0.f);
                float y6 = fmaxf(bf2f((unsigned short)(av.w & 0xffff)) * scb.z + shb.z, 0.f);
                float y7 = fmaxf(bf2f((unsigned short)(av.w >> 16)) * scb.w + shb.w, 0.f);
                uint4 ov;
                ov.x = (unsigned)f2bf(y0) | ((unsigned)f2bf(y1) << 16);
                ov.y = (unsigned)f2bf(y2) | ((unsigned)f2bf(y3) << 16);
                ov.z = (unsigned)f2bf(y4) | ((unsigned)f2bf(y5) << 16);
                ov.w = (unsigned)f2bf(y6) | ((unsigned)f2bf(y7) << 16);
                *(uint4*)(dst + (j * 8) * TK) = ov;
            }
        }
        if (notlast) {
#pragma unroll
            for (int j = 0; j < 4; ++j)
                gload16(Bg + (size_t)(j * 8) * CO + k0 + TK, smem[p ^ 1] + TM * TK + (w * 32 + j * 8) * TK);
            // outstanding: W(k) 4, A(k+1) 4, W(k+1) 4 -> wait W(k) only
            asm volatile("s_waitcnt vmcnt(8)" ::: "memory");
        } else {
            asm volatile("s_waitcnt vmcnt(0)" ::: "memory");
        }
        asm volatile("s_waitcnt lgkmcnt(0)" ::: "memory");  // my ds_writes done
        asm volatile("s_barrier" ::: "memory");
        const unsigned short* As = smem[p];
        const unsigned short* Ws = smem[p] + TM * TK;
#pragma unroll
        for (int ks = 0; ks < 2; ++ks) {
            const int off = (q * 8 + ks * 32) ^ xr;
            v8s af[4], bw[4];
#pragma unroll
            for (int r = 0; r < 4; ++r) af[r] = *(const v8s*)(As + (nsub + r * 16 + ln) * TK + off);
#pragma unroll
            for (int c = 0; c < 4; ++c) bw[c] = *(const v8s*)(Ws + (cosub + c * 16 + ln) * TK + off);
#pragma unroll
            for (int r = 0; r < 4; ++r)
#pragma unroll
                for (int c = 0; c < 4; ++c)
                    acc[r][c] = __builtin_amdgcn_mfma_f32_16x16x32_bf16(af[r], bw[c], acc[r][c], 0, 0, 0);
        }
        if (notlast) {
            asm volatile("s_barrier" ::: "memory");
#pragma unroll
            for (int j = 0; j < 4; ++j) avc[j] = avn[j];
        }
    }

    // ---- epilogue: direct packed stores (lane holds 4 consecutive n) + stats
    const int b = (int)(rbase >> 14);
    const int nb = (int)(rbase & (NN - 1));
#pragma unroll
    for (int c = 0; c < 4; ++c) {
        float s = 0.f, sq = 0.f;
#pragma unroll
        for (int r = 0; r < 4; ++r) {
            float v0 = acc[r][c][0], v1 = acc[r][c][1], v2 = acc[r][c][2], v3 = acc[r][c][3];
            uint2 ov;
            ov.x = (unsigned)f2bf(v0) | ((unsigned)f2bf(v1) << 16);
            ov.y = (unsigned)f2bf(v2) | ((unsigned)f2bf(v3) << 16);
            *(uint2*)&h2[(((size_t)(b * CO + cb + cosub + c * 16 + ln)) << 14) + nb + nsub + r * 16 + q * 4] = ov;
            s += v0 + v1 + v2 + v3;
            sq += v0 * v0 + v1 * v1 + v2 * v2 + v3 * v3;
        }
        s += __shfl_xor(s, 16); sq += __shfl_xor(sq, 16);
        s += __shfl_xor(s, 32); sq += __shfl_xor(sq, 32);
        if (lane < 16) {
            atomicAdd(&sum2[cb + cosub + c * 16 + lane], s);
            atomicAdd(&ssq2[cb + cosub + c * 16 + lane], sq);
        }
    }
}

// ---------------- final BN2+ReLU -> fp32 out (BN2 finalize folded) ----------
__global__ void k_apply(const unsigned short* __restrict__ h2,
                        const float* __restrict__ sum2, const float* __restrict__ ssq2,
                        const float* __restrict__ g2, const float* __restrict__ b2,
                        float* __restrict__ out) {
    __shared__ float ss[2];
    int o = (blockIdx.x >> 4) & 255;   // each block spans 1024 elems within one channel
    if (threadIdx.x == 0) {
        const float invn = 1.f / (float)MTOT;
        float m = sum2[o] * invn;
        float v = ssq2[o] * invn - m * m;
        float s = g2[o] * rsqrtf(v + 1e-5f);
        ss[0] = s;
        ss[1] = b2[o] - m * s;
    }
    __syncthreads();
    float s = ss[0], d = ss[1];
    size_t i = ((size_t)blockIdx.x * 256 + threadIdx.x) * 4;
    ushort4 hv = *(const ushort4*)(h2 + i);
    float4 v;
    v.x = fmaxf(bf2f(hv.x) * s + d, 0.f);
    v.y = fmaxf(bf2f(hv.y) * s + d, 0.f);
    v.z = fmaxf(bf2f(hv.z) * s + d, 0.f);
    v.w = fmaxf(bf2f(hv.w) * s + d, 0.f);
    *(float4*)&out[i] = v;
}

extern "C" void kernel_launch(void* const* d_in, const int* in_sizes, int n_in,
                              void* d_out, int out_size, void* d_ws, size_t ws_size,
                              hipStream_t stream) {
    const float* p1 = (const float*)d_in[0];
    const float* p2 = (const float*)d_in[1];
    const float* f1 = (const float*)d_in[2];
    const float* f2 = (const float*)d_in[3];
    const void*  idx = d_in[4];
    const float* W1 = (const float*)d_in[5];
    const float* g1 = (const float*)d_in[6];
    const float* b1 = (const float*)d_in[7];
    const float* W2 = (const float*)d_in[8];
    const float* g2 = (const float*)d_in[9];
    const float* b2 = (const float*)d_in[10];
    float* out = (float*)d_out;

    char* ws = (char*)d_ws;
    float* stats = (float*)(ws + STATS_OFF);
    float* sum1 = stats + 0;     float* ssq1 = stats + 256;
    float* sum2 = stats + 1024;  float* ssq2 = stats + 1280;
    int* flag64 = (int*)(ws + FLAG_OFF);
    unsigned short* W1b = (unsigned short*)(ws + W1B_OFF);
    unsigned short* W2b = (unsigned short*)(ws + W2B_OFF);
    unsigned short* f2t = (unsigned short*)(ws + F2T_OFF);
    unsigned short* xT  = (unsigned short*)(ws + XT_OFF);
    unsigned short* h2  = (unsigned short*)(ws + H2_OFF);

    unsigned short* h1 = (unsigned short*)d_out;  // 67 MB bf16 scratch in d_out

    k_prep<<<577, 256, 0, stream>>>(idx, flag64, stats, W1, W1b, W2, W2b);
    k_tr_f2<<<dim3(MM / 32, C2 / 64, BB), 256, 0, stream>>>(f2, f2t);
    k_tr_f1<<<dim3(NN / 32, 1, BB), 256, 0, stream>>>(f1, xT);
    k_interp<<<MTOT / 8, 256, 0, stream>>>(p1, p2, idx, flag64, f2t, xT);
    k_gemm1<<<dim3(MTOT / TM, CO / TN), 256, 0, stream>>>(xT, W1b, h1, sum1, ssq1);
    k_gemm2<<<dim3(MTOT / TM, CO / TN), 256, 0, stream>>>(h1, W2b, sum1, ssq1, g1, b1, h2, sum2, ssq2);
    k_apply<<<(int)((size_t)out_size / 4 / 256), 256, 0, stream>>>(h2, sum2, ssq2, g2, b2, out);
}